// Round 9
// baseline (324.529 us; speedup 1.0000x reference)
//
#include <hip/hip_runtime.h>
#include <hip/hip_bf16.h>

// IO-HMM fwd/bwd chain + projection for MI355X (gfx950).
// L=256 steps, B=128 batch, S=256 states, NL=64 labels.
//
// Kernel 1 (chain): R19 = R18b store structure (coalesced deferred output
//   stores -- the R18b win, chain 215->183us, scatter-store retire tail
//   ~280cyc/step confirmed) + 8 waves x 2 M-tiles geometry RETEST.
//   Rationale: R13/R14's geometry tests were CONFOUNDED -- their 2-tile
//   variants issued 2x the scatter stores/step; correcting R14's ~2100cyc
//   for 2x store tail gives ~1540cyc for clean 8x2, BETTER than the
//   measured 1720cyc of R12-geometry-with-clean-stores (R18b). Step model
//   fitting R18b: LDS phase (16 waves x 8KB = 128KB @128B/cyc ~ 1030cyc,
//   round-robin service gates the last wave) + MFMA trail ~500 + overhead.
//   8x2 halves the LDS phase (64KB ~ 512cyc); B-frags read once, reused
//   across both M-tiles; MFMA/SIMD unchanged. Wave w stores batch rows
//   {w, w+8} as two 512B lane-linear stores. Arithmetic identical to R14
//   (passed, absmax 128). If neutral: 4-wave/SIMD overlap is essential ->
//   next lever is b128 LDS reads at R12 geometry.
// Kernel 2 (score): R11 version unchanged (gap is timed-region overhead).

typedef _Float16 half8 __attribute__((ext_vector_type(8)));
typedef _Float16 half4 __attribute__((ext_vector_type(4)));
typedef float    f32x4 __attribute__((ext_vector_type(4)));
typedef unsigned long long u64;

#define LL 256
#define BB 128
#define SS 256
#define BT 16
#define RSTR8 67   // carry/p-plane row stride in 8B units (ODD -> conflict-free)
#define RSTRO 65   // o-plane row stride in 8B units (ODD -> conflict-free)

static __device__ __forceinline__ f32x4 mfma16f(half8 a, half8 b, f32x4 c) {
  return __builtin_amdgcn_mfma_f32_16x16x32_f16(a, b, c, 0, 0, 0);
}

// LDS-only barrier: order ds ops, leave vmcnt (global loads/stores) in flight.
static __device__ __forceinline__ void lds_barrier() {
  __asm__ __volatile__("s_waitcnt lgkmcnt(0)\n\ts_barrier" ::: "memory");
}

// Round-to-nearest-even f16 pack (NOT cvt_pkrtz -- RTZ bias compounds over
// the 255-step chain into ~6% coherent shrink; R8 erratum).
static __device__ __forceinline__ u64 pack4(f32x4 v) {
  union { half4 h; u64 u; } x;
  x.h[0] = (_Float16)v[0];
  x.h[1] = (_Float16)v[1];
  x.h[2] = (_Float16)v[2];
  x.h[3] = (_Float16)v[3];
  return x.u;
}

// 16B logical fragment as two b64 reads (8B-aligned odd-stride layout).
static __device__ __forceinline__ half8 read_frag_s(const u64* plane, int row,
                                                    int kt, int q, int stride8) {
  const int o = row * stride8 + kt * 8 + q * 2;
  union { u64 u[2]; half8 v; } x;
  x.u[0] = plane[o];
  x.u[1] = plane[o + 1];
  return x.v;
}

__global__ __launch_bounds__(512, 2)
void hmm_chain(const int* __restrict__ sent, const float* __restrict__ emb,
               const float* __restrict__ T, _Float16* __restrict__ fwh,
               _Float16* __restrict__ gh)
{
  __shared__ u64 s_carry[2][BT * RSTR8]; // [buf][row*stride], single f16 plane
  __shared__ u64 v_pl[2][BT * RSTR8];    // bwd: pack4(v) mirror plane, dbuf
  __shared__ int s_tok[BT * 257];        // [batch][l], stride 257

  const int tid  = threadIdx.x;
  const int lane = tid & 63;
  const int w    = tid >> 6;   // wave 0..7 -> states [32w, 32w+32)
  const int m    = lane & 15;  // A row-in-tile / B col (= batch)
  const int q    = lane >> 4;  // quad

  const int  bid = blockIdx.x;
  const bool fwd = (bid < 8);
  const int  bg0 = (fwd ? bid : bid - 8) * BT;
  _Float16* const obuf = fwd ? fwh : gh;

  // ---- stage sentence tokens ----
  for (int idx = tid; idx < BT * LL; idx += 512) {
    int bb = idx >> 8, l2 = idx & 255;
    s_tok[bb * 257 + l2] = sent[(bg0 + bb) * LL + l2];
  }
  __syncthreads();

  // ---- load T fragments (A operand), 2 M-tiles x 8 K-frags = 64 regs
  half8 a_hi[2][8];
#pragma unroll
  for (int t = 0; t < 2; ++t) {
    const int r0 = 32 * w + 16 * t + m;    // state (M index)
#pragma unroll
    for (int kt = 0; kt < 8; ++kt) {
      const int kb = 32 * kt + 8 * q;      // k base
      float v[8];
      if (fwd) {
        f32x4 f0 = *(const f32x4*)(T + r0 * 256 + kb);
        f32x4 f1 = *(const f32x4*)(T + r0 * 256 + kb + 4);
#pragma unroll
        for (int j = 0; j < 4; ++j) { v[j] = f0[j]; v[4 + j] = f1[j]; }
      } else {
#pragma unroll
        for (int j = 0; j < 8; ++j) v[j] = T[(kb + j) * 256 + r0]; // T^T
      }
      half8 hi;
#pragma unroll
      for (int j = 0; j < 8; ++j) hi[j] = (_Float16)v[j];   // RNE
      a_hi[t][kt] = hi;
    }
  }

  // ---- init carry at l0; bwd also inits v_pl[0] = 1 (step-0 output g[l0])
  const int l0 = fwd ? 0 : (LL - 1);
  {
    const int tok0 = s_tok[m * 257 + l0];
    f32x4 one = 1.0f;
    const u64 pone = pack4(one);
#pragma unroll
    for (int t = 0; t < 2; ++t) {
      const int st = 32 * w + 16 * t + 4 * q;     // this lane's first state
      f32x4 e0 = *(const f32x4*)(emb + (size_t)tok0 * 256 + st);
      u64 pc = pack4(e0);                         // carry = em[l0] both dirs
      s_carry[0][m * RSTR8 + 8 * w + 4 * t + q] = pc;
      if (!fwd) v_pl[0][m * RSTR8 + 8 * w + 4 * t + q] = pone;  // g[L-1]=1
    }
  }

  // ---- prefetch em for step 1 (both tiles) ----
  f32x4 em_pref[2];
  {
    const int l1 = fwd ? 1 : (LL - 2);
    const int tok1 = s_tok[m * 257 + l1];
#pragma unroll
    for (int t = 0; t < 2; ++t)
      em_pref[t] = *(const f32x4*)(emb + (size_t)tok1 * 256 + 32 * w + 16 * t + 4 * q);
  }
  __syncthreads();

  // ---- main chain ----
  // Step s stores step s-1's output COALESCED: wave w reads batch-rows
  // {w, w+8} of the s-1 output plane (fwd: carry; bwd: v_pl) lane-linear
  // and issues two 512B stores (8 full lines each).
  for (int s = 1; s < LL; ++s) {
    const int lp = fwd ? (s - 1) : (LL - s);   // prev step's l
    const int rb = (s - 1) & 1, wb = s & 1;

    const u64* pr = &s_carry[rb][0];
    half8 bfr[8];
#pragma unroll
    for (int kt = 0; kt < 8; ++kt)
      bfr[kt] = read_frag_s(pr, m, kt, q, RSTR8);

    // deferred out-row reads for step s-1 (coalesced stores issued below)
    const u64* op = fwd ? &s_carry[rb][0] : &v_pl[rb][0];
    u64 ov0 = op[w * RSTR8 + lane];
    u64 ov1 = op[(w + 8) * RSTR8 + lane];

    // consume prefetched em; issue next prefetch (token from LDS)
    f32x4 em_now[2];
#pragma unroll
    for (int t = 0; t < 2; ++t) em_now[t] = em_pref[t];
    {
      const int ln = fwd ? (s + 1 < LL ? s + 1 : LL - 1)
                         : ((LL - 2) - s > 0 ? (LL - 2) - s : 0);
      const int tokn = s_tok[m * 257 + ln];
#pragma unroll
      for (int t = 0; t < 2; ++t)
        em_pref[t] = *(const f32x4*)(emb + (size_t)tokn * 256 + 32 * w + 16 * t + 4 * q);
    }

    // single-product f16 matmul: 16 MFMA/wave/step, B-frags read ONCE and
    // reused across both M-tiles (the LDS-traffic halving).
    f32x4 acc[2];
#pragma unroll
    for (int t = 0; t < 2; ++t) acc[t] = 0.0f;
#pragma unroll
    for (int kt = 0; kt < 8; ++kt)
#pragma unroll
      for (int t = 0; t < 2; ++t)
        acc[t] = mfma16f(a_hi[t][kt], bfr[kt], acc[t]);

#pragma unroll
    for (int t = 0; t < 2; ++t) {
      f32x4 cn = acc[t] * em_now[t];      // new carry
      u64 p0 = pack4(cn);
      s_carry[wb][m * RSTR8 + 8 * w + 4 * t + q] = p0;
      if (!fwd)
        v_pl[wb][m * RSTR8 + 8 * w + 4 * t + q] = pack4(acc[t]); // g[l]=v
    }

    // coalesced 512B stores of the previous step's rows (8 full lines each)
    _Float16* orow = obuf + ((size_t)lp * BB + bg0) * SS;
    *(u64*)(orow + (size_t)w * SS + lane * 4)       = ov0;
    *(u64*)(orow + (size_t)(w + 8) * SS + lane * 4) = ov1;

    lds_barrier();  // LDS ordering only; global stores/loads stay in flight
  }

  // ---- epilogue: store the final step's rows (plane 1 = step 255) ----
  {
    const int lp = fwd ? (LL - 1) : 0;
    const u64* op = fwd ? &s_carry[1][0] : &v_pl[1][0];
    u64 ov0 = op[w * RSTR8 + lane];
    u64 ov1 = op[(w + 8) * RSTR8 + lane];
    _Float16* orow = obuf + ((size_t)lp * BB + bg0) * SS;
    *(u64*)(orow + (size_t)w * SS + lane * 4)       = ov0;
    *(u64*)(orow + (size_t)(w + 8) * SS + lane * 4) = ov1;
  }
}

__global__ __launch_bounds__(256, 2)
void hmm_score(const _Float16* __restrict__ fwh, const _Float16* __restrict__ gh,
               const float* __restrict__ outm, float* __restrict__ score)
{
  __shared__ u64 p_pl[64 * RSTR8];   // p = fw*g, [row][k] f16
  __shared__ u64 o_pl[64 * RSTRO];   // outm^T,   [n][k]  f16

  const int tid  = threadIdx.x;
  const int lane = tid & 63;
  const int w    = tid >> 6;
  const int rh   = w >> 1;     // row half: rows [32rh, 32rh+32)
  const int np   = w & 1;      // n-pair: n-tiles {2np, 2np+1}
  const int m    = lane & 15;
  const int q    = lane >> 4;
  const int R0   = blockIdx.x * 64;  // row = l*128 + b

  // ---- stage outm -> o_pl[n][k] f16 (RNE, hi only), coalesced f32x4 loads
  {
    _Float16* o_h = (_Float16*)o_pl;
    for (int i = tid; i < 4096; i += 256) {
      f32x4 v = *(const f32x4*)(outm + i * 4);   // flat = k*64+n
      int k = i >> 4, n0 = (i & 15) * 4;
#pragma unroll
      for (int r = 0; r < 4; ++r)
        o_h[(n0 + r) * (RSTRO * 4) + k] = (_Float16)v[r];
    }
  }

  // ---- stage p = fw * g (f16 packed mul, RNE) ----
  for (int idx = tid; idx < 64 * 64; idx += 256) {
    int row = idx >> 6, c = idx & 63;       // c = 8B column index
    union { u64 u; half4 h; } a, b, p;
    a.u = *(const u64*)(fwh + (size_t)(R0 + row) * 256 + c * 4);
    b.u = *(const u64*)(gh  + (size_t)(R0 + row) * 256 + c * 4);
    p.h = a.h * b.h;                        // v_pk_mul_f16 x2
    p_pl[row * RSTR8 + c] = p.u;
  }
  lds_barrier();

  f32x4 acc[2][2];
#pragma unroll
  for (int j = 0; j < 2; ++j)
#pragma unroll
    for (int jn = 0; jn < 2; ++jn) acc[j][jn] = 0.0f;

#pragma unroll
  for (int kt = 0; kt < 8; ++kt) {
    half8 of[2];
#pragma unroll
    for (int jn = 0; jn < 2; ++jn)
      of[jn] = read_frag_s(o_pl, 16 * (2 * np + jn) + m, kt, q, RSTRO);
#pragma unroll
    for (int j = 0; j < 2; ++j) {
      half8 pf = read_frag_s(p_pl, 32 * rh + 16 * j + m, kt, q, RSTR8);
#pragma unroll
      for (int jn = 0; jn < 2; ++jn)
        acc[j][jn] = mfma16f(pf, of[jn], acc[j][jn]);
    }
  }

#pragma unroll
  for (int j = 0; j < 2; ++j) {
#pragma unroll
    for (int jn = 0; jn < 2; ++jn) {
#pragma unroll
      for (int r = 0; r < 4; ++r) {
        int row = R0 + 32 * rh + 16 * j + 4 * q + r;
        int l = row >> 7, b = row & 127;
        score[(size_t)b * 16384 + l * 64 + 16 * (2 * np + jn) + m] = acc[j][jn][r];
      }
    }
  }
}

extern "C" void kernel_launch(void* const* d_in, const int* in_sizes, int n_in,
                              void* d_out, int out_size, void* d_ws, size_t ws_size,
                              hipStream_t stream) {
  (void)in_sizes; (void)n_in; (void)out_size; (void)ws_size;
  const int*   sent = (const int*)d_in[0];
  const float* emb  = (const float*)d_in[1];
  const float* T    = (const float*)d_in[2];
  const float* outm = (const float*)d_in[3];
  _Float16* fwh = (_Float16*)d_ws;                  // [L][B][S] f16, 16 MB
  _Float16* gh  = fwh + (size_t)LL * BB * SS;       // [L][B][S] f16, 16 MB

  hmm_chain<<<16, 512, 0, stream>>>(sent, emb, T, fwh, gh);
  hmm_score<<<512, 256, 0, stream>>>(fwh, gh, outm, (float*)d_out);
}

// Round 10
// 267.749 us; speedup vs baseline: 1.2121x; 1.2121x over previous
//
#include <hip/hip_runtime.h>
#include <hip/hip_bf16.h>

// IO-HMM fwd/bwd chain + projection for MI355X (gfx950).
// L=256 steps, B=128 batch, S=256 states, NL=64 labels.
//
// Kernel 1 (chain): R20 = R18b (16 waves x 1 M-tile + coalesced deferred
//   stores, chain 183us) + b128 B-frag reads. Ledger: R19 (8x2, clean
//   stores) regressed to 247us -> the 8x2 traffic cut loses more to
//   exposed latency at 2 waves/SIMD than it saves; structural invariant:
//   bytes/chain-step = W_chain x 8KB (carry broadcast), and every packing/
//   K-split variant I costed keeps the product or adds a barrier. R20
//   attacks the RATE: 256 ds_read_b64/step/CU -> 128 ds_read_b128 (same
//   bytes, half the instrs; m134: per-instr overhead makes b128 ~2x B/cyc
//   of b32). Layout: carry/v_pl planes at row stride 528B (33x16B, odd),
//   16B-aligned frags. Bank audit: frag reads uniform 8/bank (1024B floor),
//   carry writes uniform 4/bank (floor), ov reads uniform -> no conflict
//   regression. Arithmetic bit-identical to R18b (layout only).
//   If neutral: LDS phase is at the bank-array floor -> decomposition is
//   within ~15% of structural ceiling.
// Kernel 2 (score): R11 version unchanged (gap is timed-region overhead).

typedef _Float16 half8 __attribute__((ext_vector_type(8)));
typedef _Float16 half4 __attribute__((ext_vector_type(4)));
typedef float    f32x4 __attribute__((ext_vector_type(4)));
typedef unsigned long long u64;
typedef u64 u64v2 __attribute__((ext_vector_type(2)));

#define LL 256
#define BB 128
#define SS 256
#define BT 16
#define CSTR 66    // chain plane row stride in u64 units (528B = 33x16B, ODD16)
#define RSTR8 67   // score p-plane row stride in 8B units (ODD -> conflict-free)
#define RSTRO 65   // score o-plane row stride in 8B units (ODD -> conflict-free)

static __device__ __forceinline__ f32x4 mfma16f(half8 a, half8 b, f32x4 c) {
  return __builtin_amdgcn_mfma_f32_16x16x32_f16(a, b, c, 0, 0, 0);
}

// LDS-only barrier: order ds ops, leave vmcnt (global loads/stores) in flight.
static __device__ __forceinline__ void lds_barrier() {
  __asm__ __volatile__("s_waitcnt lgkmcnt(0)\n\ts_barrier" ::: "memory");
}

// Round-to-nearest-even f16 pack (NOT cvt_pkrtz -- RTZ bias compounds over
// the 255-step chain into ~6% coherent shrink; R8 erratum).
static __device__ __forceinline__ u64 pack4(f32x4 v) {
  union { half4 h; u64 u; } x;
  x.h[0] = (_Float16)v[0];
  x.h[1] = (_Float16)v[1];
  x.h[2] = (_Float16)v[2];
  x.h[3] = (_Float16)v[3];
  return x.u;
}

// Chain B-frag: ONE ds_read_b128 (16B-aligned, stride 528B).
// Lane (m,q) frag kt = states [32kt+8q, +8) of batch-row m.
static __device__ __forceinline__ half8 read_frag16(const u64* plane, int row,
                                                    int kt, int q) {
  const int o = row * CSTR + kt * 8 + q * 2;   // u64 units, even -> 16B aligned
  union { u64v2 u; half8 v; } x;
  x.u = *(const u64v2*)(plane + o);
  return x.v;
}

// Score-kernel fragment: two b64 reads (8B-aligned odd-stride layout).
static __device__ __forceinline__ half8 read_frag_s(const u64* plane, int row,
                                                    int kt, int q, int stride8) {
  const int o = row * stride8 + kt * 8 + q * 2;
  union { u64 u[2]; half8 v; } x;
  x.u[0] = plane[o];
  x.u[1] = plane[o + 1];
  return x.v;
}

__global__ __launch_bounds__(1024, 4)
void hmm_chain(const int* __restrict__ sent, const float* __restrict__ emb,
               const float* __restrict__ T, _Float16* __restrict__ fwh,
               _Float16* __restrict__ gh)
{
  __shared__ alignas(16) u64 s_carry[2][BT * CSTR]; // [buf][row*stride] f16 plane
  __shared__ alignas(16) u64 v_pl[2][BT * CSTR];    // bwd: pack4(v) mirror, dbuf
  __shared__ int s_tok[BT * 257];                   // [batch][l], stride 257

  const int tid  = threadIdx.x;
  const int lane = tid & 63;
  const int w    = tid >> 6;   // wave 0..15 -> states [16w, 16w+16)
  const int m    = lane & 15;  // A row-in-tile / B col (= batch)
  const int q    = lane >> 4;  // quad

  const int  bid = blockIdx.x;
  const bool fwd = (bid < 8);
  const int  bg0 = (fwd ? bid : bid - 8) * BT;
  _Float16* const obuf = fwd ? fwh : gh;
  const int  st  = 16 * w + 4 * q;       // this lane's first state

  // ---- stage sentence tokens ----
  for (int idx = tid; idx < BT * LL; idx += 1024) {
    int bb = idx >> 8, l2 = idx & 255;
    s_tok[bb * 257 + l2] = sent[(bg0 + bb) * LL + l2];
  }
  __syncthreads();

  // ---- load T fragments (A operand), single f16: 8 frags = 32 regs
  half8 a_hi[8];
#pragma unroll
  for (int kt = 0; kt < 8; ++kt) {
    const int r0 = 16 * w + m;           // state (M index)
    const int kb = 32 * kt + 8 * q;      // k base
    float v[8];
    if (fwd) {
      f32x4 f0 = *(const f32x4*)(T + r0 * 256 + kb);
      f32x4 f1 = *(const f32x4*)(T + r0 * 256 + kb + 4);
#pragma unroll
      for (int j = 0; j < 4; ++j) { v[j] = f0[j]; v[4 + j] = f1[j]; }
    } else {
#pragma unroll
      for (int j = 0; j < 8; ++j) v[j] = T[(kb + j) * 256 + r0]; // T^T
    }
    half8 hi;
#pragma unroll
    for (int j = 0; j < 8; ++j) hi[j] = (_Float16)v[j];   // RNE
    a_hi[kt] = hi;
  }

  // ---- init carry at l0; bwd also inits v_pl[0] = 1 (step-0 output g[l0])
  const int l0 = fwd ? 0 : (LL - 1);
  {
    const int tok0 = s_tok[m * 257 + l0];
    f32x4 e0 = *(const f32x4*)(emb + (size_t)tok0 * 256 + st);
    u64 pc = pack4(e0);                       // carry = em[l0] both dirs
    s_carry[0][m * CSTR + 4 * w + q] = pc;
    if (!fwd) {
      f32x4 one = 1.0f;
      v_pl[0][m * CSTR + 4 * w + q] = pack4(one);  // g[L-1] = 1
    }
  }

  // ---- prefetch em for step 1 ----
  f32x4 em_pref;
  {
    const int l1 = fwd ? 1 : (LL - 2);
    const int tok1 = s_tok[m * 257 + l1];
    em_pref = *(const f32x4*)(emb + (size_t)tok1 * 256 + st);
  }
  __syncthreads();

  // ---- main chain ----
  // Step s stores step s-1's output COALESCED: wave w reads batch-row w of
  // the s-1 output plane (fwd: carry; bwd: v_pl) lane-linear and issues ONE
  // 512B store (8 full lines).
  for (int s = 1; s < LL; ++s) {
    const int lp = fwd ? (s - 1) : (LL - s);   // prev step's l
    const int rb = (s - 1) & 1, wb = s & 1;

    const u64* pr = &s_carry[rb][0];
    half8 bfr[8];
#pragma unroll
    for (int kt = 0; kt < 8; ++kt)
      bfr[kt] = read_frag16(pr, m, kt, q);     // 8x ds_read_b128

    // deferred out-row read for step s-1 (coalesced store issued below)
    const u64* op = fwd ? &s_carry[rb][0] : &v_pl[rb][0];
    u64 ov = op[w * CSTR + lane];

    // consume prefetched em; issue next prefetch (token from LDS)
    f32x4 em_now = em_pref;
    {
      const int ln = fwd ? (s + 1 < LL ? s + 1 : LL - 1)
                         : ((LL - 2) - s > 0 ? (LL - 2) - s : 0);
      const int tokn = s_tok[m * 257 + ln];
      em_pref = *(const f32x4*)(emb + (size_t)tokn * 256 + st);
    }

    // single-product f16 matmul (8 MFMA/wave/step)
    f32x4 hh = 0.0f;
#pragma unroll
    for (int kt = 0; kt < 8; ++kt)
      hh = mfma16f(a_hi[kt], bfr[kt], hh);
    f32x4 v  = hh;                     // pre-em matmul result
    f32x4 cn = v * em_now;             // new carry

    u64 p0 = pack4(cn);
    s_carry[wb][m * CSTR + 4 * w + q] = p0;
    if (!fwd)
      v_pl[wb][m * CSTR + 4 * w + q] = pack4(v);  // g[l] = v (bit-identical)

    // coalesced 512B store of the previous step's row (8 full lines)
    *(u64*)(obuf + ((size_t)lp * BB + bg0 + w) * SS + lane * 4) = ov;

    lds_barrier();  // LDS ordering only; global stores/loads stay in flight
  }

  // ---- epilogue: store the final step's row (plane 1 = step 255) ----
  {
    const int lp = fwd ? (LL - 1) : 0;
    const u64* op = fwd ? &s_carry[1][0] : &v_pl[1][0];
    u64 ov = op[w * CSTR + lane];
    *(u64*)(obuf + ((size_t)lp * BB + bg0 + w) * SS + lane * 4) = ov;
  }
}

__global__ __launch_bounds__(256, 2)
void hmm_score(const _Float16* __restrict__ fwh, const _Float16* __restrict__ gh,
               const float* __restrict__ outm, float* __restrict__ score)
{
  __shared__ u64 p_pl[64 * RSTR8];   // p = fw*g, [row][k] f16
  __shared__ u64 o_pl[64 * RSTRO];   // outm^T,   [n][k]  f16

  const int tid  = threadIdx.x;
  const int lane = tid & 63;
  const int w    = tid >> 6;
  const int rh   = w >> 1;     // row half: rows [32rh, 32rh+32)
  const int np   = w & 1;      // n-pair: n-tiles {2np, 2np+1}
  const int m    = lane & 15;
  const int q    = lane >> 4;
  const int R0   = blockIdx.x * 64;  // row = l*128 + b

  // ---- stage outm -> o_pl[n][k] f16 (RNE, hi only), coalesced f32x4 loads
  {
    _Float16* o_h = (_Float16*)o_pl;
    for (int i = tid; i < 4096; i += 256) {
      f32x4 v = *(const f32x4*)(outm + i * 4);   // flat = k*64+n
      int k = i >> 4, n0 = (i & 15) * 4;
#pragma unroll
      for (int r = 0; r < 4; ++r)
        o_h[(n0 + r) * (RSTRO * 4) + k] = (_Float16)v[r];
    }
  }

  // ---- stage p = fw * g (f16 packed mul, RNE) ----
  for (int idx = tid; idx < 64 * 64; idx += 256) {
    int row = idx >> 6, c = idx & 63;       // c = 8B column index
    union { u64 u; half4 h; } a, b, p;
    a.u = *(const u64*)(fwh + (size_t)(R0 + row) * 256 + c * 4);
    b.u = *(const u64*)(gh  + (size_t)(R0 + row) * 256 + c * 4);
    p.h = a.h * b.h;                        // v_pk_mul_f16 x2
    p_pl[row * RSTR8 + c] = p.u;
  }
  lds_barrier();

  f32x4 acc[2][2];
#pragma unroll
  for (int j = 0; j < 2; ++j)
#pragma unroll
    for (int jn = 0; jn < 2; ++jn) acc[j][jn] = 0.0f;

#pragma unroll
  for (int kt = 0; kt < 8; ++kt) {
    half8 of[2];
#pragma unroll
    for (int jn = 0; jn < 2; ++jn)
      of[jn] = read_frag_s(o_pl, 16 * (2 * np + jn) + m, kt, q, RSTRO);
#pragma unroll
    for (int j = 0; j < 2; ++j) {
      half8 pf = read_frag_s(p_pl, 32 * rh + 16 * j + m, kt, q, RSTR8);
#pragma unroll
      for (int jn = 0; jn < 2; ++jn)
        acc[j][jn] = mfma16f(pf, of[jn], acc[j][jn]);
    }
  }

#pragma unroll
  for (int j = 0; j < 2; ++j) {
#pragma unroll
    for (int jn = 0; jn < 2; ++jn) {
#pragma unroll
      for (int r = 0; r < 4; ++r) {
        int row = R0 + 32 * rh + 16 * j + 4 * q + r;
        int l = row >> 7, b = row & 127;
        score[(size_t)b * 16384 + l * 64 + 16 * (2 * np + jn) + m] = acc[j][jn][r];
      }
    }
  }
}

extern "C" void kernel_launch(void* const* d_in, const int* in_sizes, int n_in,
                              void* d_out, int out_size, void* d_ws, size_t ws_size,
                              hipStream_t stream) {
  (void)in_sizes; (void)n_in; (void)out_size; (void)ws_size;
  const int*   sent = (const int*)d_in[0];
  const float* emb  = (const float*)d_in[1];
  const float* T    = (const float*)d_in[2];
  const float* outm = (const float*)d_in[3];
  _Float16* fwh = (_Float16*)d_ws;                  // [L][B][S] f16, 16 MB
  _Float16* gh  = fwh + (size_t)LL * BB * SS;       // [L][B][S] f16, 16 MB

  hmm_chain<<<16, 1024, 0, stream>>>(sent, emb, T, fwh, gh);
  hmm_score<<<512, 256, 0, stream>>>(fwh, gh, outm, (float*)d_out);
}